// Round 4
// baseline (942.288 us; speedup 1.0000x reference)
//
#include <hip/hip_runtime.h>

typedef unsigned int u32;
typedef unsigned short u16;
typedef __attribute__((ext_vector_type(4))) float floatx4;
typedef __attribute__((ext_vector_type(8))) __bf16 bf16x8;

#define T_ 2048
#define D_ 2048
#define DL_ 1024
#define E_ 64
#define I_ 768
#define SI_ 4096
#define TOPK 6
#define NGRP 8
#define TOPG 4
#define CAP_ 384

#define BM 128
#define BK 32

__device__ __forceinline__ u16 f2bf(float f) {
  u32 u = __builtin_bit_cast(u32, f);
  u += 0x7fffu + ((u >> 16) & 1u);  // RNE to bf16 (finite data)
  return (u16)(u >> 16);
}
__device__ __forceinline__ float bf2f(u16 h) {
  return __builtin_bit_cast(float, ((u32)h) << 16);
}

__device__ __forceinline__ void async16(const u16* g, u16* l) {
  __builtin_amdgcn_global_load_lds((const __attribute__((address_space(1))) void*)g,
                                   (__attribute__((address_space(3))) void*)l, 16, 0, 0);
}

// ---------------- fp32 -> bf16 streaming convert (x only) ----------------
__global__ __launch_bounds__(256) void cvt_f2b_k(const float* __restrict__ src,
                                                 u16* __restrict__ dst, int n8) {
  int i = blockIdx.x * 256 + threadIdx.x;
  if (i >= n8) return;
  const float4* s4 = (const float4*)src;
  float4 a = s4[2 * i], b = s4[2 * i + 1];
  u32 p0 = (u32)f2bf(a.x) | ((u32)f2bf(a.y) << 16);
  u32 p1 = (u32)f2bf(a.z) | ((u32)f2bf(a.w) << 16);
  u32 p2 = (u32)f2bf(b.x) | ((u32)f2bf(b.y) << 16);
  u32 p3 = (u32)f2bf(b.z) | ((u32)f2bf(b.w) << 16);
  ((uint4*)dst)[i] = make_uint4(p0, p1, p2, p3);
}

// ---------------- gate logits ----------------
__global__ __launch_bounds__(256) void gate_logits_k(const float* __restrict__ x,
                                                     const float* __restrict__ gw,
                                                     float* __restrict__ logits) {
  __shared__ float xs[16 * 65];
  __shared__ float wsd[32 * 65];
  const int tid = threadIdx.x;
  const int t0 = blockIdx.x * 16;
  const int e0 = blockIdx.y * 32;
  const int tl = tid & 15, eb = (tid >> 4) * 2;
  const int xr = tid >> 4, xc = (tid & 15) * 4;
  const int wr = tid >> 3, wc = (tid & 7) * 8;
  float acc[2] = {0.f, 0.f};
  for (int kc = 0; kc < D_; kc += 64) {
    __syncthreads();
    float4 xv = *(const float4*)&x[(size_t)(t0 + xr) * D_ + kc + xc];
    xs[xr * 65 + xc + 0] = xv.x;
    xs[xr * 65 + xc + 1] = xv.y;
    xs[xr * 65 + xc + 2] = xv.z;
    xs[xr * 65 + xc + 3] = xv.w;
#pragma unroll
    for (int i = 0; i < 2; ++i) {
      float4 wv = *(const float4*)&gw[(size_t)(e0 + wr) * D_ + kc + wc + i * 4];
      wsd[wr * 65 + wc + i * 4 + 0] = wv.x;
      wsd[wr * 65 + wc + i * 4 + 1] = wv.y;
      wsd[wr * 65 + wc + i * 4 + 2] = wv.z;
      wsd[wr * 65 + wc + i * 4 + 3] = wv.w;
    }
    __syncthreads();
#pragma unroll 4
    for (int kk = 0; kk < 64; ++kk) {
      float xvv = xs[tl * 65 + kk];
      acc[0] += xvv * wsd[eb * 65 + kk];
      acc[1] += xvv * wsd[(eb + 1) * 65 + kk];
    }
  }
  logits[(size_t)(t0 + tl) * E_ + e0 + eb + 0] = acc[0];
  logits[(size_t)(t0 + tl) * E_ + e0 + eb + 1] = acc[1];
}

// ---------------- routing: one token per wave ----------------
__global__ __launch_bounds__(256) void route_k(const float* __restrict__ logits,
                                               const float* __restrict__ bias,
                                               int* __restrict__ cnts,
                                               int* __restrict__ etok,
                                               int* __restrict__ row_of,
                                               float* __restrict__ tww) {
  const int wid = threadIdx.x >> 6, lane = threadIdx.x & 63;
  const int t = blockIdx.x * 4 + wid;
  float lg = logits[(size_t)t * E_ + lane];
  float s = 1.f / (1.f + __expf(-lg));
  float sb = s + bias[lane];
  const int g = lane >> 3;
  float m1 = sb;
  m1 = fmaxf(m1, __shfl_xor(m1, 1));
  m1 = fmaxf(m1, __shfl_xor(m1, 2));
  m1 = fmaxf(m1, __shfl_xor(m1, 4));
  unsigned long long b1 = __ballot(sb == m1);
  int am = __ffsll((unsigned long long)((b1 >> (g * 8)) & 0xFFull)) - 1 + g * 8;
  float v2 = (lane == am) ? -1e30f : sb;
  float m2 = v2;
  m2 = fmaxf(m2, __shfl_xor(m2, 1));
  m2 = fmaxf(m2, __shfl_xor(m2, 2));
  m2 = fmaxf(m2, __shfl_xor(m2, 4));
  float gs = m1 + m2;
  float gsv[NGRP];
#pragma unroll
  for (int gg = 0; gg < NGRP; ++gg) gsv[gg] = __shfl(gs, gg * 8);
  unsigned selm = 0;
#pragma unroll
  for (int r = 0; r < TOPG; ++r) {
    float best = -1e30f; int bi = 0;
#pragma unroll
    for (int gg = 0; gg < NGRP; ++gg)
      if (!((selm >> gg) & 1) && gsv[gg] > best) { best = gsv[gg]; bi = gg; }
    selm |= 1u << bi;
  }
  float val = ((selm >> g) & 1) ? sb : 0.0f;
  float wsum = 0.f; int selr = -1;
#pragma unroll
  for (int r = 0; r < TOPK; ++r) {
    float m = val;
    m = fmaxf(m, __shfl_xor(m, 1));
    m = fmaxf(m, __shfl_xor(m, 2));
    m = fmaxf(m, __shfl_xor(m, 4));
    m = fmaxf(m, __shfl_xor(m, 8));
    m = fmaxf(m, __shfl_xor(m, 16));
    m = fmaxf(m, __shfl_xor(m, 32));
    unsigned long long b2 = __ballot(val == m);
    int am2 = __ffsll(b2) - 1;
    if (lane == am2) { selr = r; val = -1e30f; }
    wsum += __shfl(s, am2);
  }
  float inv = 2.5f / (wsum + 1e-20f);
  if (selr >= 0) {
    int slot = atomicAdd(&cnts[lane], 1);
    int rowid = -1;
    if (slot < CAP_) { rowid = lane * CAP_ + slot; etok[rowid] = t; }
    row_of[t * TOPK + selr] = rowid;
    tww[t * TOPK + selr] = s * inv;
  }
}

// ---------------- GEMM: A bf16 (async->LDS), B fp32 (reg->convert->LDS) ----------------
// C[M,N] = A[M,K] * B[N,K]^T
// EPI: 0 = bf16 store, 1 = relu2 bf16 store, 2 = fp32 store, 3 = fp32 accumulate
// One barrier per K-iter; A/B/Breg all double-buffered, prefetch 1 iter ahead.
template <int BNT, int EPI, bool GATHER, bool FUSED>
__global__ __launch_bounds__(256) void gemm_bw(
    const u16* __restrict__ A, const float* __restrict__ B0, void* __restrict__ C0,
    int M, int K, int ldA, int ldB, int ldC0,
    long sAe, long sBe, long sCe,
    const int* __restrict__ counts, const int* __restrict__ gather,
    int nsplit, const float* __restrict__ B2, void* __restrict__ C2, int ldC2) {
  constexpr int NJ = BNT / 32;          // N accumulator tiles per wave
  constexpr int EPT = BNT * BK / 256;   // fp32 elems per thread for B staging
  constexpr int NF4 = EPT / 4;          // float4 loads per thread
  constexpr int TPR = BK / EPT;         // threads per B row
  __shared__ u16 smem[16384];           // 32 KB: staging (As dbuf + Bs dbuf) / C bounce
  u16* AsB = smem;                      // [2][BM*BK]
  u16* BsB = smem + 2 * BM * BK;        // [2][BNT*BK]

  const int e = blockIdx.z;
  int Mloc = M;
  if (counts) { Mloc = counts[e]; if (Mloc > CAP_) Mloc = CAP_; }
  const int m0 = blockIdx.y * BM;
  if (m0 >= Mloc) return;
  const int n0 = blockIdx.x * BNT;
  const int tid = threadIdx.x;
  const int wave = tid >> 6, lane = tid & 63;
  const int lrow = lane >> 2, lcol = (lane & 3) * 8;

  // A source pointers (per-lane, fixed over K)
  int ar0 = m0 + wave * 32 + lrow, ar1 = ar0 + 16;
  const u16 *aS0, *aS1;
  if (GATHER) {
    int t0i = (ar0 < Mloc) ? gather[e * CAP_ + ar0] : 0;
    int t1i = (ar1 < Mloc) ? gather[e * CAP_ + ar1] : 0;
    aS0 = A + (size_t)t0i * ldA + lcol;
    aS1 = A + (size_t)t1i * ldA + lcol;
  } else {
    aS0 = A + (size_t)e * sAe + (size_t)ar0 * ldA + lcol;
    aS1 = A + (size_t)e * sAe + (size_t)ar1 * ldA + lcol;
  }
  // B source pointer (fp32)
  const float* Bsel;
  int n0loc = n0;
  if (FUSED) {
    if (n0 < nsplit) { Bsel = B0; } else { Bsel = B2; n0loc = n0 - nsplit; }
  } else {
    Bsel = B0 + (size_t)e * sBe;
  }
  const int brow = tid / TPR;
  const int bkc = (tid % TPR) * EPT;
  const float* Bln = Bsel + (size_t)(n0loc + brow) * ldB + bkc;

  auto issueA = [&](int kt, int p) {
    u16* base = AsB + p * (BM * BK);
    async16(aS0 + kt, base + (wave * 32 + 0) * BK);
    async16(aS1 + kt, base + (wave * 32 + 16) * BK);
  };
  float4 rA[NF4], rB[NF4];
  auto loadB = [&](int kt, float4* r) {
#pragma unroll
    for (int f = 0; f < NF4; ++f) r[f] = *(const float4*)(Bln + kt + f * 4);
  };
  auto writeB = [&](const float4* r, int p) {
    u32 w[EPT / 2];
#pragma unroll
    for (int f = 0; f < NF4; ++f) {
      w[2 * f]     = (u32)f2bf(r[f].x) | ((u32)f2bf(r[f].y) << 16);
      w[2 * f + 1] = (u32)f2bf(r[f].z) | ((u32)f2bf(r[f].w) << 16);
    }
    uint4* dst = (uint4*)(BsB + p * (BNT * BK) + brow * BK + bkc);
#pragma unroll
    for (int f = 0; f < NF4 / 2; ++f)
      dst[f] = make_uint4(w[4 * f], w[4 * f + 1], w[4 * f + 2], w[4 * f + 3]);
  };

  floatx4 acc[4][NJ];
#pragma unroll
  for (int i = 0; i < 4; ++i)
#pragma unroll
    for (int j = 0; j < NJ; ++j) acc[i][j] = floatx4{0.f, 0.f, 0.f, 0.f};

  const int wm = (wave & 1) * 64;
  const int wn = (wave >> 1) * (NJ * 16);
  const int lr = lane & 15, lk = (lane >> 4) * 8;

  auto compute = [&](int p) {
    const u16* Ab = AsB + p * (BM * BK);
    const u16* Bb = BsB + p * (BNT * BK);
    bf16x8 af[4], bfr[NJ];
#pragma unroll
    for (int i = 0; i < 4; ++i)
      af[i] = *(const bf16x8*)&Ab[(wm + i * 16 + lr) * BK + lk];
#pragma unroll
    for (int j = 0; j < NJ; ++j)
      bfr[j] = *(const bf16x8*)&Bb[(wn + j * 16 + lr) * BK + lk];
#pragma unroll
    for (int i = 0; i < 4; ++i)
#pragma unroll
      for (int j = 0; j < NJ; ++j)
        acc[i][j] = __builtin_amdgcn_mfma_f32_16x16x32_bf16(af[i], bfr[j], acc[i][j], 0, 0, 0);
  };

  // prologue: tile 0 fully staged; B(BK) in regs
  loadB(0, rA);
  writeB(rA, 0);
  issueA(0, 0);
  loadB(BK, rB);
  // K/BK is even for all our shapes
  for (int kt = 0; kt < K; kt += 2 * BK) {
    __syncthreads();  // As[0]/Bs[0] ready; rB holds B(kt+BK)
    if (kt + BK < K) { issueA(kt + BK, 1); writeB(rB, 1); }
    if (kt + 2 * BK < K) loadB(kt + 2 * BK, rA);
    compute(0);
    __syncthreads();  // As[1]/Bs[1] ready; rA holds B(kt+2BK)
    if (kt + 2 * BK < K) { issueA(kt + 2 * BK, 0); writeB(rA, 0); }
    if (kt + 3 * BK < K) loadB(kt + 3 * BK, rB);
    compute(1);
  }

  // ---- epilogue: bounce through LDS for vectorized stores ----
  __syncthreads();
  const int rbase = (lane >> 4) * 4;
  if constexpr (EPI <= 1) {
    bool doRelu = (EPI == 1);
    void* Cq = C0; int ldC = ldC0; int nc0 = n0;
    if (FUSED) {
      if (n0 < nsplit) { doRelu = true; }
      else { Cq = C2; ldC = ldC2; nc0 = n0 - nsplit; doRelu = false; }
    }
    u16* Cs = smem;  // BM x BNT bf16 (<= 32KB)
#pragma unroll
    for (int i = 0; i < 4; ++i)
#pragma unroll
      for (int r = 0; r < 4; ++r)
#pragma unroll
        for (int j = 0; j < NJ; ++j) {
          float v = acc[i][j][r];
          if (doRelu) { v = fmaxf(v, 0.f); v *= v; }
          Cs[(wm + i * 16 + rbase + r) * BNT + wn + j * 16 + lr] = f2bf(v);
        }
    __syncthreads();
    const int srow = tid >> 1, sc0 = (tid & 1) * (BNT / 2);
    if (m0 + srow < Mloc) {
      u16* gdst = (u16*)Cq + (size_t)sCe * e + (size_t)(m0 + srow) * ldC + nc0 + sc0;
      const u16* ssrc = Cs + srow * BNT + sc0;
#pragma unroll
      for (int q = 0; q < BNT / 16; ++q)
        ((uint4*)gdst)[q] = ((const uint4*)ssrc)[q];
    }
  } else {
    static_assert(BNT == 64 || EPI <= 1, "fp32 bounce needs BNT=64");
    float* Cs = (float*)smem;  // BM x 64 fp32 = 32KB
#pragma unroll
    for (int i = 0; i < 4; ++i)
#pragma unroll
      for (int r = 0; r < 4; ++r)
#pragma unroll
        for (int j = 0; j < NJ; ++j)
          Cs[(wm + i * 16 + rbase + r) * BNT + wn + j * 16 + lr] = acc[i][j][r];
    __syncthreads();
    const int srow = tid >> 1, sc0 = (tid & 1) * (BNT / 2);
    if (m0 + srow < Mloc) {
      float* gdst = (float*)C0 + (size_t)(m0 + srow) * ldC0 + n0 + sc0;
      const float* ssrc = Cs + srow * BNT + sc0;
#pragma unroll
      for (int q = 0; q < BNT / 8; ++q) {
        float4 v = ((const float4*)ssrc)[q];
        if constexpr (EPI == 3) {
          float4 o = ((const float4*)gdst)[q];
          v.x += o.x; v.y += o.y; v.z += o.z; v.w += o.w;
        }
        ((float4*)gdst)[q] = v;
      }
    }
  }
}

// ---------------- fallback fp32-B GEMM (round-1 path, small ws) ----------------
#define LDS_PAD 40
#define BNF 128
template <int ATYPE, int EPI>
__global__ __launch_bounds__(256, 2) void gemm_nt(const void* __restrict__ Ap,
                                                  const float* __restrict__ Bp,
                                                  void* __restrict__ Cp,
                                                  int M, int K, int ldA, int ldB, int ldC,
                                                  long sAe, long sBe, long sCe,
                                                  const int* __restrict__ counts,
                                                  const int* __restrict__ gather) {
  __shared__ u16 As[BM * LDS_PAD];
  __shared__ u16 Bs[BNF * LDS_PAD];
  const int e = blockIdx.z;
  int Mloc = M;
  if (counts) { Mloc = counts[e]; if (Mloc > CAP_) Mloc = CAP_; }
  const int m0 = blockIdx.y * BM;
  if (m0 >= Mloc) return;
  const int n0 = blockIdx.x * BNF;
  const int tid = threadIdx.x;
  const int row = tid >> 1;
  const int colb = (tid & 1) * 16;
  const int arow = m0 + row;
  int arowIdx;
  if (gather) arowIdx = (arow < Mloc) ? gather[e * CAP_ + arow] : 0;
  else arowIdx = arow;
  const float* Af32 = (const float*)Ap + (size_t)e * sAe + (size_t)arowIdx * ldA;
  const u16* Abf = (const u16*)Ap + (size_t)e * sAe + (size_t)arowIdx * ldA;
  const float* Brow = Bp + (size_t)e * sBe + (size_t)(n0 + row) * ldB;
  float4 ra[4]; uint4 rab[2]; float4 rb[4];
  auto loadAB = [&](int kt) {
    if constexpr (ATYPE == 0) {
#pragma unroll
      for (int i = 0; i < 4; ++i) ra[i] = *(const float4*)&Af32[kt + colb + i * 4];
    } else {
#pragma unroll
      for (int i = 0; i < 2; ++i) rab[i] = *(const uint4*)&Abf[kt + colb + i * 8];
    }
#pragma unroll
    for (int i = 0; i < 4; ++i) rb[i] = *(const float4*)&Brow[kt + colb + i * 4];
  };
  auto stage = [&]() {
    uint4* ad = (uint4*)&As[row * LDS_PAD + colb];
    if constexpr (ATYPE == 0) {
      u32 w[8];
#pragma unroll
      for (int i = 0; i < 4; ++i) {
        w[2 * i] = (u32)f2bf(ra[i].x) | ((u32)f2bf(ra[i].y) << 16);
        w[2 * i + 1] = (u32)f2bf(ra[i].z) | ((u32)f2bf(ra[i].w) << 16);
      }
      ad[0] = make_uint4(w[0], w[1], w[2], w[3]);
      ad[1] = make_uint4(w[4], w[5], w[6], w[7]);
    } else {
      ad[0] = rab[0]; ad[1] = rab[1];
    }
    u32 wb[8];
#pragma unroll
    for (int i = 0; i < 4; ++i) {
      wb[2 * i] = (u32)f2bf(rb[i].x) | ((u32)f2bf(rb[i].y) << 16);
      wb[2 * i + 1] = (u32)f2bf(rb[i].z) | ((u32)f2bf(rb[i].w) << 16);
    }
    uint4* bd = (uint4*)&Bs[row * LDS_PAD + colb];
    bd[0] = make_uint4(wb[0], wb[1], wb[2], wb[3]);
    bd[1] = make_uint4(wb[4], wb[5], wb[6], wb[7]);
  };
  floatx4 acc[4][4];
#pragma unroll
  for (int i = 0; i < 4; ++i)
#pragma unroll
    for (int j = 0; j < 4; ++j) acc[i][j] = floatx4{0.f, 0.f, 0.f, 0.f};
  const int wave = tid >> 6, lane = tid & 63;
  const int wm = (wave & 1) * 64, wn = (wave >> 1) * 64;
  const int lr = lane & 15, lk = (lane >> 4) * 8;
  loadAB(0);
  for (int kt = 0; kt < K; kt += BK) {
    __syncthreads();
    stage();
    __syncthreads();
    if (kt + BK < K) loadAB(kt + BK);
    bf16x8 af[4], bfr[4];
#pragma unroll
    for (int i = 0; i < 4; ++i)
      af[i] = *(const bf16x8*)&As[(wm + i * 16 + lr) * LDS_PAD + lk];
#pragma unroll
    for (int j = 0; j < 4; ++j)
      bfr[j] = *(const bf16x8*)&Bs[(wn + j * 16 + lr) * LDS_PAD + lk];
#pragma unroll
    for (int i = 0; i < 4; ++i)
#pragma unroll
      for (int j = 0; j < 4; ++j)
        acc[i][j] = __builtin_amdgcn_mfma_f32_16x16x32_bf16(af[i], bfr[j], acc[i][j], 0, 0, 0);
  }
  const int rbase = (lane >> 4) * 4;
#pragma unroll
  for (int i = 0; i < 4; ++i) {
#pragma unroll
    for (int r = 0; r < 4; ++r) {
      int grow = m0 + wm + i * 16 + rbase + r;
      if (grow >= Mloc) continue;
      size_t crow = (size_t)sCe * e + (size_t)grow * ldC;
#pragma unroll
      for (int j = 0; j < 4; ++j) {
        int gcol = n0 + wn + j * 16 + lr;
        float v = acc[i][j][r];
        if constexpr (EPI == 0) {
          ((u16*)Cp)[crow + gcol] = f2bf(v);
        } else if constexpr (EPI == 1) {
          v = fmaxf(v, 0.f); v *= v;
          ((u16*)Cp)[crow + gcol] = f2bf(v);
        } else if constexpr (EPI == 2) {
          ((float*)Cp)[crow + gcol] = v;
        } else {
          ((float*)Cp)[crow + gcol] += v;
        }
      }
    }
  }
}

// ---------------- combine ----------------
__global__ __launch_bounds__(256) void combine_k(const u16* __restrict__ eout,
                                                 const int* __restrict__ row_of,
                                                 const float* __restrict__ tww,
                                                 u16* __restrict__ ylat) {
  int t = blockIdx.x;
  int c0 = threadIdx.x * 4;
  float a0 = 0.f, a1 = 0.f, a2 = 0.f, a3 = 0.f;
#pragma unroll
  for (int k = 0; k < TOPK; ++k) {
    int r = row_of[t * TOPK + k];
    float w = tww[t * TOPK + k];
    if (r >= 0) {
      uint2 v = *(const uint2*)&eout[(size_t)r * DL_ + c0];
      a0 += w * bf2f((u16)(v.x & 0xffffu));
      a1 += w * bf2f((u16)(v.x >> 16));
      a2 += w * bf2f((u16)(v.y & 0xffffu));
      a3 += w * bf2f((u16)(v.y >> 16));
    }
  }
  u32 o0 = (u32)f2bf(a0) | ((u32)f2bf(a1) << 16);
  u32 o1 = (u32)f2bf(a2) | ((u32)f2bf(a3) << 16);
  *(uint2*)&ylat[(size_t)t * DL_ + c0] = make_uint2(o0, o1);
}

extern "C" void kernel_launch(void* const* d_in, const int* in_sizes, int n_in,
                              void* d_out, int out_size, void* d_ws, size_t ws_size,
                              hipStream_t stream) {
  (void)in_sizes; (void)n_in; (void)out_size;
  const float* x = (const float*)d_in[0];
  const float* gw = (const float*)d_in[1];
  const float* gbias = (const float*)d_in[2];
  const float* fc1 = (const float*)d_in[3];
  const float* fc2 = (const float*)d_in[4];
  const float* w1 = (const float*)d_in[5];
  const float* w2 = (const float*)d_in[6];
  const float* sw1 = (const float*)d_in[7];
  const float* sw2 = (const float*)d_in[8];
  float* out = (float*)d_out;

  char* ws = (char*)d_ws;
  size_t off = 0;
  auto alloc = [&](size_t bytes) {
    char* p = ws + off;
    off += (bytes + 255) & ~(size_t)255;
    return p;
  };
  float* logits = (float*)alloc((size_t)T_ * E_ * 4);
  int* cnts = (int*)alloc(E_ * 4);
  int* etok = (int*)alloc((size_t)E_ * CAP_ * 4);
  int* row_of = (int*)alloc((size_t)T_ * TOPK * 4);
  float* tww = (float*)alloc((size_t)T_ * TOPK * 4);
  u16* xl = (u16*)alloc((size_t)T_ * DL_ * 2);
  u16* ylat = (u16*)alloc((size_t)T_ * DL_ * 2);

  size_t big1_elems = (size_t)E_ * CAP_ * I_;  // 18.9M >= T_*SI_ (8.4M)
  if ((size_t)T_ * SI_ > big1_elems) big1_elems = (size_t)T_ * SI_;
  size_t need_fast = off + (((size_t)T_ * D_ * 2 + 255) & ~255ul)        // xbf
                     + ((big1_elems * 2 + 255) & ~255ul)                 // hs/h
                     + (((size_t)E_ * CAP_ * DL_ * 2 + 255) & ~255ul);   // eout

  hipMemsetAsync(cnts, 0, E_ * 4, stream);
  gate_logits_k<<<dim3(T_ / 16, 2), 256, 0, stream>>>(x, gw, logits);
  route_k<<<T_ / 4, 256, 0, stream>>>(logits, gbias, cnts, etok, row_of, tww);

  if (ws_size >= need_fast) {
    u16* xbf = (u16*)alloc((size_t)T_ * D_ * 2);
    u16* big1 = (u16*)alloc(big1_elems * 2);                // hs then h
    u16* eoutB = (u16*)alloc((size_t)E_ * CAP_ * DL_ * 2);

    cvt_f2b_k<<<(T_ * D_ / 8 + 255) / 256, 256, 0, stream>>>(x, xbf, T_ * D_ / 8);

    // fused: [hs | xl] = x @ [sw1 | fc1]^T  (hs gets relu2, xl plain)
    gemm_bw<128, 1, false, true><<<dim3((SI_ + DL_) / 128, T_ / BM, 1), 256, 0, stream>>>(
        xbf, sw1, big1, T_, D_, D_, D_, SI_, 0, 0, 0, nullptr, nullptr,
        SI_, fc1, xl, DL_);

    // shared2: out = hs @ sw2^T (fp32 store)
    gemm_bw<64, 2, false, false><<<dim3(D_ / 64, T_ / BM, 1), 256, 0, stream>>>(
        big1, sw2, out, T_, SI_, SI_, SI_, D_, 0, 0, 0, nullptr, nullptr,
        0, nullptr, nullptr, 0);

    // expert1: h = relu2(gather(xl) @ w1[e]^T)  (overwrites big1 after shared2 consumed hs)
    gemm_bw<128, 1, true, false><<<dim3(I_ / 128, CAP_ / BM, E_), 256, 0, stream>>>(
        xl, w1, big1, CAP_, DL_, DL_, DL_, I_,
        0, (long)I_ * DL_, (long)CAP_ * I_, cnts, etok, 0, nullptr, nullptr, 0);

    // expert2: eout = h @ w2[e]^T
    gemm_bw<128, 0, false, false><<<dim3(DL_ / 128, CAP_ / BM, E_), 256, 0, stream>>>(
        big1, w2, eoutB, CAP_, I_, I_, I_, DL_,
        (long)CAP_ * I_, (long)DL_ * I_, (long)CAP_ * DL_, cnts, nullptr, 0, nullptr, nullptr, 0);

    combine_k<<<T_, 256, 0, stream>>>(eoutB, row_of, tww, ylat);

    // fc2: out += ylat @ fc2^T (fp32 accumulate)
    gemm_bw<64, 3, false, false><<<dim3(D_ / 64, T_ / BM, 1), 256, 0, stream>>>(
        ylat, fc2, out, T_, DL_, DL_, DL_, D_, 0, 0, 0, nullptr, nullptr,
        0, nullptr, nullptr, 0);
  } else {
    char* big = alloc((size_t)E_ * CAP_ * I_ * 2 + (size_t)E_ * CAP_ * DL_ * 2);
    u16* hs = (u16*)big;
    u16* h = (u16*)big;
    u16* eoutB = (u16*)(big + (size_t)E_ * CAP_ * I_ * 2);

    gemm_nt<0, 1><<<dim3(SI_ / BNF, T_ / BM, 1), 256, 0, stream>>>(
        x, sw1, hs, T_, D_, D_, D_, SI_, 0, 0, 0, nullptr, nullptr);
    gemm_nt<1, 2><<<dim3(D_ / BNF, T_ / BM, 1), 256, 0, stream>>>(
        hs, sw2, out, T_, SI_, SI_, SI_, D_, 0, 0, 0, nullptr, nullptr);
    gemm_nt<0, 0><<<dim3(DL_ / BNF, T_ / BM, 1), 256, 0, stream>>>(
        x, fc1, xl, T_, D_, D_, D_, DL_, 0, 0, 0, nullptr, nullptr);
    gemm_nt<1, 1><<<dim3(I_ / BNF, CAP_ / BM, E_), 256, 0, stream>>>(
        xl, w1, h, CAP_, DL_, DL_, DL_, I_,
        0, (long)I_ * DL_, (long)CAP_ * I_, cnts, etok);
    gemm_nt<1, 0><<<dim3(DL_ / BNF, CAP_ / BM, E_), 256, 0, stream>>>(
        h, w2, eoutB, CAP_, I_, I_, I_, DL_,
        (long)CAP_ * I_, (long)DL_ * I_, (long)CAP_ * DL_, cnts, nullptr);
    combine_k<<<T_, 256, 0, stream>>>(eoutB, row_of, tww, ylat);
    gemm_nt<1, 3><<<dim3(D_ / BNF, T_ / BM, 1), 256, 0, stream>>>(
        ylat, fc2, out, T_, DL_, DL_, DL_, D_, 0, 0, 0, nullptr, nullptr);
  }
}